// Round 12
// baseline (528.714 us; speedup 1.0000x reference)
//
#include <hip/hip_runtime.h>
#include <hip/hip_bf16.h>

#define N_NODES 50000
#define N_EDGES 800000
#define DIM 128
#define NLAYER 3
#define NEG 0.2f

typedef __attribute__((ext_vector_type(8))) short short8;
typedef __attribute__((ext_vector_type(4))) float f32x4;

// ---------------- CSR build ----------------
__global__ __launch_bounds__(256) void hist_kernel(const int* __restrict__ dst, int* __restrict__ counts) {
    int e = blockIdx.x * 256 + threadIdx.x;
    if (e < N_EDGES) atomicAdd(&counts[dst[e]], 1);
}

// scan1 also re-zeroes counts (it is reused as the place-cursor)
__global__ __launch_bounds__(256) void scan1_kernel(int* __restrict__ counts, int* __restrict__ indptr,
                                                    int* __restrict__ bsum, int n) {
    __shared__ int buf[256];
    int t = threadIdx.x;
    int i = blockIdx.x * 256 + t;
    int v = (i < n) ? counts[i] : 0;
    buf[t] = v;
    __syncthreads();
    for (int off = 1; off < 256; off <<= 1) {
        int add = (t >= off) ? buf[t - off] : 0;
        __syncthreads();
        buf[t] += add;
        __syncthreads();
    }
    if (i < n) {
        indptr[i + 1] = buf[t];
        counts[i] = 0;  // cursor for place_kernel
    }
    if (t == 255) bsum[blockIdx.x] = buf[255];
}

__global__ __launch_bounds__(256) void scan2_kernel(int* __restrict__ bsum, int* __restrict__ boff,
                                                    int* __restrict__ indptr, int nb) {
    __shared__ int buf[256];
    int t = threadIdx.x;
    int v = (t < nb) ? bsum[t] : 0;
    buf[t] = v;
    __syncthreads();
    for (int off = 1; off < 256; off <<= 1) {
        int add = (t >= off) ? buf[t - off] : 0;
        __syncthreads();
        buf[t] += add;
        __syncthreads();
    }
    if (t < nb) boff[t] = buf[t] - v;  // exclusive
    if (t == 0) indptr[0] = 0;
}

__global__ __launch_bounds__(256) void scan3_kernel(int* __restrict__ indptr, const int* __restrict__ boff, int n) {
    int i = blockIdx.x * 256 + threadIdx.x;
    if (i < n) indptr[i + 1] += boff[i >> 8];
}

__global__ __launch_bounds__(256) void place_kernel(const int* __restrict__ srcp, const int* __restrict__ dstp,
                                                    const int* __restrict__ indptr, int* __restrict__ cursor,
                                                    int* __restrict__ csr_src, int* __restrict__ csr_dst,
                                                    int* __restrict__ csr_eid) {
    int e = blockIdx.x * 256 + threadIdx.x;
    if (e < N_EDGES) {
        int dn = dstp[e];
        int pos = indptr[dn] + atomicAdd(&cursor[dn], 1);
        csr_src[pos] = srcp[e];
        csr_dst[pos] = dn;
        csr_eid[pos] = e;
    }
}

// ---------------- weight prep: split W into bf16 hi/lo, transposed [n][k]; also zero counts ----------------
__global__ __launch_bounds__(256) void prep_weights_kernel(const float* __restrict__ Wl, const float* __restrict__ Wr,
                                                           const float* __restrict__ c1W,
                                                           unsigned short* __restrict__ wt,
                                                           int* __restrict__ counts) {
    int idx = blockIdx.x * 256 + threadIdx.x;  // 8 * 16384 = 131072
    if (idx < N_NODES) counts[idx] = 0;
    int m = idx >> 14;
    int r = idx & 16383;
    int n = r >> 7, k = r & 127;
    int L = m >> 1, half = m & 1;
    const float* W;
    if (L < 3) W = (half ? Wr : Wl) + (size_t)L * 16384;
    else W = c1W + (size_t)half * 16384;
    float v = W[k * 128 + n];
    __hip_bfloat16 hb = __float2bfloat16(v);
    float rl = v - __bfloat162float(hb);
    __hip_bfloat16 lb = __float2bfloat16(rl);
    wt[(size_t)m * 32768 + n * 128 + k] = *reinterpret_cast<unsigned short*>(&hb);
    wt[(size_t)m * 32768 + 16384 + n * 128 + k] = *reinterpret_cast<unsigned short*>(&lb);
}

// ---------------- dual GEMM via split-bf16 MFMA; bf16 outputs; optional fused encoder ----------------
// ENC: input hx is x [N][5]; h-tile computed inline as relu(x @ encW + encb)
template <bool ENC>
__global__ __launch_bounds__(256) void transform_mfma_kernel(const float* __restrict__ hx,
                                                             const unsigned short* __restrict__ wtA,
                                                             const float* __restrict__ bA,
                                                             const unsigned short* __restrict__ wtB,
                                                             const float* __restrict__ bB,
                                                             __hip_bfloat16* __restrict__ outA,
                                                             __hip_bfloat16* __restrict__ outB,
                                                             const float* __restrict__ encW,
                                                             const float* __restrict__ encb) {
    __shared__ __align__(16) char hhi[64 * 256];  // bf16 [64][128], XOR-swizzled 16B rows
    __shared__ __align__(16) char hlo[64 * 256];
    __shared__ float encWs[ENC ? 640 : 1];
    __shared__ float encbs[ENC ? 128 : 1];
    int t = threadIdx.x;
    int l = t & 63, w = t >> 6;
    int n0 = blockIdx.x * 64;

    if constexpr (ENC) {
        for (int i = t; i < 640; i += 256) encWs[i] = encW[i];
        if (t < 128) encbs[t] = encb[t];
        __syncthreads();
    }

    for (int i = t; i < 64 * 32; i += 256) {
        int row = i >> 5, c4 = (i & 31) * 4;
        int n = n0 + row;
        float4 v = make_float4(0.f, 0.f, 0.f, 0.f);
        if (n < N_NODES) {
            if constexpr (ENC) {
                float xv[5];
#pragma unroll
                for (int f = 0; f < 5; f++) xv[f] = hx[(size_t)n * 5 + f];
                float* pv = &v.x;
#pragma unroll
                for (int q = 0; q < 4; q++) {
                    int d = c4 + q;
                    float a = encbs[d];
#pragma unroll
                    for (int f = 0; f < 5; f++) a += xv[f] * encWs[f * 128 + d];
                    pv[q] = fmaxf(a, 0.f);
                }
            } else {
                v = *(const float4*)&hx[(size_t)n * DIM + c4];
            }
        }
        const float* pv = &v.x;
        unsigned short hi4[4], lo4[4];
#pragma unroll
        for (int q = 0; q < 4; q++) {
            __hip_bfloat16 hb = __float2bfloat16(pv[q]);
            float rl = pv[q] - __bfloat162float(hb);
            __hip_bfloat16 lb = __float2bfloat16(rl);
            hi4[q] = *reinterpret_cast<unsigned short*>(&hb);
            lo4[q] = *reinterpret_cast<unsigned short*>(&lb);
        }
        int addr = (row * 256 + c4 * 2) ^ ((row & 7) << 4);
        *(ushort4*)(hhi + addr) = make_ushort4(hi4[0], hi4[1], hi4[2], hi4[3]);
        *(ushort4*)(hlo + addr) = make_ushort4(lo4[0], lo4[1], lo4[2], lo4[3]);
    }
    __syncthreads();

    int lane_m = l & 15, lane_k8 = l >> 4;

#pragma unroll
    for (int mat = 0; mat < 2; mat++) {
        const short* wthi = (const short*)(mat ? wtB : wtA);
        const short* wtlo = wthi + 16384;
        const float* bias = mat ? bB : bA;
        short8 bh[2][4], bl_[2][4];
#pragma unroll
        for (int j = 0; j < 2; j++) {
            int nrow = (w * 2 + j) * 16 + lane_m;
#pragma unroll
            for (int ks = 0; ks < 4; ks++) {
                int ke = ks * 32 + lane_k8 * 8;
                bh[j][ks] = *(const short8*)(wthi + nrow * 128 + ke);
                bl_[j][ks] = *(const short8*)(wtlo + nrow * 128 + ke);
            }
        }
        f32x4 acc[4][2];
#pragma unroll
        for (int mt = 0; mt < 4; mt++)
#pragma unroll
            for (int j = 0; j < 2; j++) acc[mt][j] = (f32x4){0.f, 0.f, 0.f, 0.f};
#pragma unroll
        for (int ks = 0; ks < 4; ks++) {
            int kb = ks * 64 + lane_k8 * 16;
#pragma unroll
            for (int mt = 0; mt < 4; mt++) {
                int arow = mt * 16 + lane_m;
                int aswz = (arow & 7) << 4;
                short8 ahi = *(const short8*)(hhi + ((arow * 256 + kb) ^ aswz));
                short8 alo = *(const short8*)(hlo + ((arow * 256 + kb) ^ aswz));
#pragma unroll
                for (int j = 0; j < 2; j++) {
                    acc[mt][j] = __builtin_amdgcn_mfma_f32_16x16x32_bf16(ahi, bh[j][ks], acc[mt][j], 0, 0, 0);
                    acc[mt][j] = __builtin_amdgcn_mfma_f32_16x16x32_bf16(ahi, bl_[j][ks], acc[mt][j], 0, 0, 0);
                    acc[mt][j] = __builtin_amdgcn_mfma_f32_16x16x32_bf16(alo, bh[j][ks], acc[mt][j], 0, 0, 0);
                }
            }
        }
        __hip_bfloat16* outp = mat ? outB : outA;
#pragma unroll
        for (int j = 0; j < 2; j++) {
            int col = (w * 2 + j) * 16 + lane_m;
            float bv = bias ? bias[col] : 0.f;
#pragma unroll
            for (int mt = 0; mt < 4; mt++) {
#pragma unroll
                for (int r = 0; r < 4; r++) {
                    int node = n0 + mt * 16 + lane_k8 * 4 + r;
                    if (node < N_NODES) {
                        outp[(size_t)node * DIM + col] = __float2bfloat16(acc[mt][j][r] + bv);
                    }
                }
            }
        }
    }
}

// ---------------- GATv2 edge+aggregate v6: wave-per-node, bf16 xl+xr gathers, 8 edges/iter ----------------
__device__ __forceinline__ float4 bf4_to_f4(ushort4 u) {
    float4 v;
    v.x = __uint_as_float((unsigned)u.x << 16);
    v.y = __uint_as_float((unsigned)u.y << 16);
    v.z = __uint_as_float((unsigned)u.z << 16);
    v.w = __uint_as_float((unsigned)u.w << 16);
    return v;
}

__global__ __launch_bounds__(256) void gat_edge_kernel(const unsigned short* __restrict__ xl,
                                                       const unsigned short* __restrict__ xr,
                                                       const float* __restrict__ att, const float* __restrict__ gbias,
                                                       const int* __restrict__ indptr, const int* __restrict__ csr_src,
                                                       float* __restrict__ h_out) {
    int n = blockIdx.x * 4 + (threadIdx.x >> 6);  // wave-per-node
    int l = threadIdx.x & 63;
    int half = l >> 5;
    int c0 = (l & 31) * 4;
    float4 xrv = bf4_to_f4(*(const ushort4*)&xr[(size_t)n * DIM + c0]);
    float4 attv = *(const float4*)&att[c0];
    int beg = indptr[n], end = indptr[n + 1];

    float m[4], den[4];
    float4 acc[4];
    // self-loop seeds chain 0 of half 0
    {
        float4 v = bf4_to_f4(*(const ushort4*)&xl[(size_t)n * DIM + c0]);
        float z, a;
        z = v.x + xrv.x; z = fmaxf(z, NEG * z); a = z * attv.x;
        z = v.y + xrv.y; z = fmaxf(z, NEG * z); a += z * attv.y;
        z = v.z + xrv.z; z = fmaxf(z, NEG * z); a += z * attv.z;
        z = v.w + xrv.w; z = fmaxf(z, NEG * z); a += z * attv.w;
        a += __shfl_xor(a, 1);
        a += __shfl_xor(a, 2);
        a += __shfl_xor(a, 4);
        if (half == 0) {
            m[0] = a; den[0] = 1.f; acc[0] = v;
        } else {
            m[0] = -3.4e38f; den[0] = 0.f; acc[0] = make_float4(0.f, 0.f, 0.f, 0.f);
        }
#pragma unroll
        for (int c = 1; c < 4; c++) { m[c] = -3.4e38f; den[c] = 0.f; acc[c] = make_float4(0.f, 0.f, 0.f, 0.f); }
    }

    for (int i = beg; i < end; i += 8) {
        int s[4];
        bool val[4];
        float4 v[4];
        float a[4];
#pragma unroll
        for (int c = 0; c < 4; c++) {
            int idx = i + 2 * c + half;
            val[c] = idx < end;
            s[c] = val[c] ? csr_src[idx] : n;
        }
#pragma unroll
        for (int c = 0; c < 4; c++) v[c] = bf4_to_f4(*(const ushort4*)&xl[(size_t)s[c] * DIM + c0]);
#pragma unroll
        for (int c = 0; c < 4; c++) {
            float z, aa;
            z = v[c].x + xrv.x; z = fmaxf(z, NEG * z); aa = z * attv.x;
            z = v[c].y + xrv.y; z = fmaxf(z, NEG * z); aa += z * attv.y;
            z = v[c].z + xrv.z; z = fmaxf(z, NEG * z); aa += z * attv.z;
            z = v[c].w + xrv.w; z = fmaxf(z, NEG * z); aa += z * attv.w;
            a[c] = aa;
        }
#pragma unroll
        for (int off = 1; off <= 4; off <<= 1)
#pragma unroll
            for (int c = 0; c < 4; c++) a[c] += __shfl_xor(a[c], off);
#pragma unroll
        for (int c = 0; c < 4; c++) {
            if (!val[c]) a[c] = -3.4e38f;
            float mn = fmaxf(m[c], a[c]);
            float sc = __expf(m[c] - mn), p = __expf(a[c] - mn);
            den[c] = den[c] * sc + p;
            acc[c].x = acc[c].x * sc + p * v[c].x;
            acc[c].y = acc[c].y * sc + p * v[c].y;
            acc[c].z = acc[c].z * sc + p * v[c].z;
            acc[c].w = acc[c].w * sc + p * v[c].w;
            m[c] = mn;
        }
    }
    // merge 4 chains into chain 0 (lane-local)
#pragma unroll
    for (int c = 1; c < 4; c++) {
        float mm = fmaxf(m[0], m[c]);
        float s0 = __expf(m[0] - mm), s1 = __expf(m[c] - mm);
        den[0] = den[0] * s0 + den[c] * s1;
        acc[0].x = acc[0].x * s0 + acc[c].x * s1;
        acc[0].y = acc[0].y * s0 + acc[c].y * s1;
        acc[0].z = acc[0].z * s0 + acc[c].z * s1;
        acc[0].w = acc[0].w * s0 + acc[c].w * s1;
        m[0] = mm;
    }
    // merge across halves (lane l <-> l^32)
    {
        float mo = __shfl_xor(m[0], 32);
        float dno = __shfl_xor(den[0], 32);
        float4 ao;
        ao.x = __shfl_xor(acc[0].x, 32);
        ao.y = __shfl_xor(acc[0].y, 32);
        ao.z = __shfl_xor(acc[0].z, 32);
        ao.w = __shfl_xor(acc[0].w, 32);
        float mm = fmaxf(m[0], mo);
        float s0 = __expf(m[0] - mm), s1 = __expf(mo - mm);
        den[0] = den[0] * s0 + dno * s1;
        acc[0].x = acc[0].x * s0 + ao.x * s1;
        acc[0].y = acc[0].y * s0 + ao.y * s1;
        acc[0].z = acc[0].z * s0 + ao.z * s1;
        acc[0].w = acc[0].w * s0 + ao.w * s1;
    }
    if (half == 0) {
        float4 gb = *(const float4*)&gbias[c0];
        float inv = 1.f / (den[0] + 1e-16f);
        float4 o;
        o.x = acc[0].x * inv + gb.x;
        o.y = acc[0].y * inv + gb.y;
        o.z = acc[0].z * inv + gb.z;
        o.w = acc[0].w * inv + gb.w;
        o.x = (o.x > 0.f) ? o.x : __expf(o.x) - 1.f;
        o.y = (o.y > 0.f) ? o.y : __expf(o.y) - 1.f;
        o.z = (o.z > 0.f) ? o.z : __expf(o.z) - 1.f;
        o.w = (o.w > 0.f) ? o.w : __expf(o.w) - 1.f;
        *(float4*)&h_out[(size_t)n * DIM + c0] = o;
    }
}

// ---------------- edge MLP v8: CSR-ordered, 128-edge tiles, W2 hi/lo in registers, MFMA layer2 ----------------
#define ETILE 128
__global__ __launch_bounds__(256) void edge_mlp_kernel(const unsigned* __restrict__ g1u, const unsigned* __restrict__ g2u,
                                                       const float* __restrict__ x,
                                                       const int* __restrict__ csr_src, const int* __restrict__ csr_dst,
                                                       const int* __restrict__ csr_eid,
                                                       const float* __restrict__ W1tail,  // c1_W rows 256,257
                                                       const float* __restrict__ W2, const float* __restrict__ b2,
                                                       const float* __restrict__ W3, const float* __restrict__ b3,
                                                       float* __restrict__ out, int ntiles) {
    __shared__ __align__(16) char smO1[ETILE * 256];  // 128 edges x 128 bf16, XOR-swizzled 16B
    __shared__ float smCw[2][128];
    __shared__ float smPart[4][ETILE];
    __shared__ int rowi[ETILE], coli[ETILE], seid[ETILE];
    __shared__ float sdt[ETILE], sdi[ETILE];
    int t = threadIdx.x;
    int l = t & 63, w = t >> 6;

    if (t < 128) {
        smCw[0][t] = W1tail[t];
        smCw[1][t] = W1tail[128 + t];
    }
    float b3v = b3[0];
    float b2v = b2[w * 16 + (l & 15)];
    float w3v = W3[w * 16 + (l & 15)];
    int koff = (l >> 4) * 16;

    // loop-invariant W2^T B-fragments -> registers (hi + lo split, loaded once)
    short8 bhi[4], blo[4];
    {
        int nrow = w * 16 + (l & 15);
        int kbase = (l >> 4) * 8;
#pragma unroll
        for (int ks = 0; ks < 4; ks++) {
            int ke = ks * 32 + kbase;
            short8 h8, l8;
#pragma unroll
            for (int q = 0; q < 8; q++) {
                float v = W2[(size_t)(ke + q) * 64 + nrow];
                __hip_bfloat16 hb = __float2bfloat16(v);
                float rl = v - __bfloat162float(hb);
                __hip_bfloat16 lb = __float2bfloat16(rl);
                h8[q] = *reinterpret_cast<short*>(&hb);
                l8[q] = *reinterpret_cast<short*>(&lb);
            }
            bhi[ks] = h8;
            blo[ks] = l8;
        }
    }

    const uint4* g1t = (const uint4*)g1u;
    const uint4* g2t = (const uint4*)g2u;

    for (int tile = blockIdx.x; tile < ntiles; tile += gridDim.x) {
        int p0 = tile * ETILE;
        __syncthreads();  // prev tile fully consumed (also first-iter smCw fence)
        if (t < ETILE) {
            int p = p0 + t;
            int r = csr_src[p], c = csr_dst[p];
            rowi[t] = r; coli[t] = c; seid[t] = csr_eid[p];
            sdt[t] = fabsf(x[r * 5 + 4] - x[c * 5 + 4]);
            float dx = x[r * 5 + 1] - x[c * 5 + 1];
            float dy = x[r * 5 + 2] - x[c * 5 + 2];
            float dz = x[r * 5 + 3] - x[c * 5 + 3];
            sdi[t] = sqrtf(dx * dx + dy * dy + dz * dz);
        }
        __syncthreads();
        // build o1: each thread one 16B slot (8 dims) of one edge; 8 rounds, gathers interleaved
        for (int idx = t; idx < ETILE * 16; idx += 256) {
            int e = idx >> 4, s4 = idx & 15;
            uint4 u1 = g1t[(size_t)rowi[e] * 16 + s4];
            uint4 u2 = g2t[(size_t)coli[e] * 16 + s4];
            float dtv = sdt[e], div = sdi[e];
            unsigned uo[4];
            const unsigned* a1 = &u1.x;
            const unsigned* a2 = &u2.x;
#pragma unroll
            for (int q = 0; q < 4; q++) {
                int d = s4 * 8 + q * 2;
                float lo = __uint_as_float(a1[q] << 16) + __uint_as_float(a2[q] << 16) + dtv * smCw[0][d] + div * smCw[1][d];
                float hi = __uint_as_float(a1[q] & 0xffff0000u) + __uint_as_float(a2[q] & 0xffff0000u) +
                           dtv * smCw[0][d + 1] + div * smCw[1][d + 1];
                lo = fmaxf(lo, 0.f); hi = fmaxf(hi, 0.f);
                __hip_bfloat16 blo16 = __float2bfloat16(lo), bhi16 = __float2bfloat16(hi);
                unsigned short ulo = *reinterpret_cast<unsigned short*>(&blo16);
                unsigned short uhi = *reinterpret_cast<unsigned short*>(&bhi16);
                uo[q] = (unsigned)ulo | ((unsigned)uhi << 16);
            }
            int addr = (e * 256 + s4 * 16) ^ ((e & 7) << 4);
            *(uint4*)(smO1 + addr) = *(uint4*)uo;
        }
        __syncthreads();
        // layer 2 via MFMA (W2 hi/lo from registers); 8 m-tiles
        f32x4 acc[8];
#pragma unroll
        for (int mt = 0; mt < 8; mt++) acc[mt] = (f32x4){0.f, 0.f, 0.f, 0.f};
#pragma unroll
        for (int ks = 0; ks < 4; ks++) {
#pragma unroll
            for (int mt = 0; mt < 8; mt++) {
                int mrow = mt * 16 + (l & 15);
                short8 afrag = *(const short8*)(smO1 + ((mrow * 256 + koff + ks * 64) ^ ((mrow & 7) << 4)));
                acc[mt] = __builtin_amdgcn_mfma_f32_16x16x32_bf16(afrag, bhi[ks], acc[mt], 0, 0, 0);
                acc[mt] = __builtin_amdgcn_mfma_f32_16x16x32_bf16(afrag, blo[ks], acc[mt], 0, 0, 0);
            }
        }
        // layer 3
        float p[8][4];
#pragma unroll
        for (int mt = 0; mt < 8; mt++)
#pragma unroll
            for (int r = 0; r < 4; r++) p[mt][r] = fmaxf(acc[mt][r] + b2v, 0.f) * w3v;
#pragma unroll
        for (int off = 8; off >= 1; off >>= 1)
#pragma unroll
            for (int mt = 0; mt < 8; mt++)
#pragma unroll
                for (int r = 0; r < 4; r++) p[mt][r] += __shfl_xor(p[mt][r], off);
        if ((l & 15) == 0) {
            int g = l >> 4;
#pragma unroll
            for (int mt = 0; mt < 8; mt++)
#pragma unroll
                for (int r = 0; r < 4; r++) smPart[w][mt * 16 + g * 4 + r] = p[mt][r];
        }
        __syncthreads();
        if (t < ETILE) out[seid[t]] = smPart[0][t] + smPart[1][t] + smPart[2][t] + smPart[3][t] + b3v;
    }
}

extern "C" void kernel_launch(void* const* d_in, const int* in_sizes, int n_in,
                              void* d_out, int out_size, void* d_ws, size_t ws_size,
                              hipStream_t stream) {
    const float* x = (const float*)d_in[0];
    const int* ei = (const int*)d_in[1];
    const float* enc_W = (const float*)d_in[2];
    const float* enc_b = (const float*)d_in[3];
    const float* Wl = (const float*)d_in[4];
    const float* bl = (const float*)d_in[5];
    const float* Wr = (const float*)d_in[6];
    const float* br = (const float*)d_in[7];
    const float* att = (const float*)d_in[8];
    const float* gbias = (const float*)d_in[9];
    const float* c1_W = (const float*)d_in[10];
    const float* c1_b = (const float*)d_in[11];
    const float* c2_W = (const float*)d_in[12];
    const float* c2_b = (const float*)d_in[13];
    const float* c3_W = (const float*)d_in[14];
    const float* c3_b = (const float*)d_in[15];
    float* out = (float*)d_out;

    float* h = (float*)d_ws;
    __hip_bfloat16* xl = (__hip_bfloat16*)(h + (size_t)N_NODES * DIM);  // bf16 xl / g1
    __hip_bfloat16* xr = xl + (size_t)N_NODES * DIM;                    // bf16 xr / g2
    int* csr_src = (int*)(xr + (size_t)N_NODES * DIM);
    int* csr_dst = csr_src + N_EDGES;
    int* csr_eid = csr_dst + N_EDGES;
    int* indptr = csr_eid + N_EDGES;
    int* counts = indptr + (N_NODES + 1);
    int* bsum = counts + N_NODES;
    int* boff = bsum + 256;
    uintptr_t wp = (uintptr_t)(boff + 256);
    wp = (wp + 15) & ~(uintptr_t)15;
    unsigned short* wt = (unsigned short*)wp;  // 8 matrices x {hi,lo} x 16384 bf16 = 512 KB

    const int* srcp = ei;
    const int* dstp = ei + N_EDGES;
    const int NB = (N_NODES + 255) / 256;   // 196
    const int TGRID = (N_NODES + 63) / 64;  // 782

    // weight prep (transpose + hi/lo split) + zero counts
    prep_weights_kernel<<<8 * 16384 / 256, 256, 0, stream>>>(Wl, Wr, c1_W, wt, counts);

    // CSR build
    hist_kernel<<<N_EDGES / 256, 256, 0, stream>>>(dstp, counts);
    scan1_kernel<<<NB, 256, 0, stream>>>(counts, indptr, bsum, N_NODES);
    scan2_kernel<<<1, 256, 0, stream>>>(bsum, boff, indptr, NB);
    scan3_kernel<<<NB, 256, 0, stream>>>(indptr, boff, N_NODES);
    place_kernel<<<N_EDGES / 256, 256, 0, stream>>>(srcp, dstp, indptr, counts, csr_src, csr_dst, csr_eid);

    // GAT layers (xl, xr both bf16); layer 0 fuses the encoder
    for (int i = 0; i < NLAYER; i++) {
        if (i == 0) {
            transform_mfma_kernel<true><<<TGRID, 256, 0, stream>>>(
                x, wt + (size_t)0 * 32768, bl,
                wt + (size_t)1 * 32768, br, xl, xr, enc_W, enc_b);
        } else {
            transform_mfma_kernel<false><<<TGRID, 256, 0, stream>>>(
                h, wt + (size_t)(i * 2) * 32768, bl + (size_t)i * DIM,
                wt + (size_t)(i * 2 + 1) * 32768, br + (size_t)i * DIM, xl, xr, nullptr, nullptr);
        }
        gat_edge_kernel<<<N_NODES / 4, 256, 0, stream>>>((const unsigned short*)xl, (const unsigned short*)xr,
                                                         att + (size_t)i * DIM,
                                                         gbias + (size_t)i * DIM, indptr, csr_src, h);
    }

    // classifier layer-1 node-level split: g1 = h@W1a + b1, g2 = h@W1b (both bf16)
    transform_mfma_kernel<false><<<TGRID, 256, 0, stream>>>(
        h, wt + (size_t)6 * 32768, c1_b, wt + (size_t)7 * 32768, nullptr, xl, xr, nullptr, nullptr);

    // fused edge MLP (CSR-ordered, 128-edge tiles, register-W2 MFMA layer2)
    edge_mlp_kernel<<<1024, 256, 0, stream>>>((const unsigned*)xl, (const unsigned*)xr, x,
                                              csr_src, csr_dst, csr_eid, c1_W + 256 * DIM,
                                              c2_W, c2_b, c3_W, c3_b, out, N_EDGES / ETILE);
}

// Round 13
// 514.547 us; speedup vs baseline: 1.0275x; 1.0275x over previous
//
#include <hip/hip_runtime.h>
#include <hip/hip_bf16.h>

#define N_NODES 50000
#define N_EDGES 800000
#define DIM 128
#define NLAYER 3
#define NEG 0.2f

typedef __attribute__((ext_vector_type(8))) short short8;
typedef __attribute__((ext_vector_type(4))) float f32x4;

// ---------------- CSR build ----------------
__global__ __launch_bounds__(256) void hist_kernel(const int* __restrict__ dst, int* __restrict__ counts) {
    int e = blockIdx.x * 256 + threadIdx.x;
    if (e < N_EDGES) atomicAdd(&counts[dst[e]], 1);
}

// scan1 also re-zeroes counts (it is reused as the place-cursor)
__global__ __launch_bounds__(256) void scan1_kernel(int* __restrict__ counts, int* __restrict__ indptr,
                                                    int* __restrict__ bsum, int n) {
    __shared__ int buf[256];
    int t = threadIdx.x;
    int i = blockIdx.x * 256 + t;
    int v = (i < n) ? counts[i] : 0;
    buf[t] = v;
    __syncthreads();
    for (int off = 1; off < 256; off <<= 1) {
        int add = (t >= off) ? buf[t - off] : 0;
        __syncthreads();
        buf[t] += add;
        __syncthreads();
    }
    if (i < n) {
        indptr[i + 1] = buf[t];
        counts[i] = 0;  // cursor for place_kernel
    }
    if (t == 255) bsum[blockIdx.x] = buf[255];
}

__global__ __launch_bounds__(256) void scan2_kernel(int* __restrict__ bsum, int* __restrict__ boff,
                                                    int* __restrict__ indptr, int nb) {
    __shared__ int buf[256];
    int t = threadIdx.x;
    int v = (t < nb) ? bsum[t] : 0;
    buf[t] = v;
    __syncthreads();
    for (int off = 1; off < 256; off <<= 1) {
        int add = (t >= off) ? buf[t - off] : 0;
        __syncthreads();
        buf[t] += add;
        __syncthreads();
    }
    if (t < nb) boff[t] = buf[t] - v;  // exclusive
    if (t == 0) indptr[0] = 0;
}

__global__ __launch_bounds__(256) void scan3_kernel(int* __restrict__ indptr, const int* __restrict__ boff, int n) {
    int i = blockIdx.x * 256 + threadIdx.x;
    if (i < n) indptr[i + 1] += boff[i >> 8];
}

__global__ __launch_bounds__(256) void place_kernel(const int* __restrict__ srcp, const int* __restrict__ dstp,
                                                    const int* __restrict__ indptr, int* __restrict__ cursor,
                                                    int* __restrict__ csr_src, int* __restrict__ csr_dst,
                                                    int* __restrict__ csr_eid) {
    int e = blockIdx.x * 256 + threadIdx.x;
    if (e < N_EDGES) {
        int dn = dstp[e];
        int pos = indptr[dn] + atomicAdd(&cursor[dn], 1);
        csr_src[pos] = srcp[e];
        csr_dst[pos] = dn;
        csr_eid[pos] = e;
    }
}

// ---------------- weight prep: split W into bf16 hi/lo, transposed [n][k]; also zero counts ----------------
__global__ __launch_bounds__(256) void prep_weights_kernel(const float* __restrict__ Wl, const float* __restrict__ Wr,
                                                           const float* __restrict__ c1W,
                                                           unsigned short* __restrict__ wt,
                                                           int* __restrict__ counts) {
    int idx = blockIdx.x * 256 + threadIdx.x;  // 8 * 16384 = 131072
    if (idx < N_NODES) counts[idx] = 0;
    int m = idx >> 14;
    int r = idx & 16383;
    int n = r >> 7, k = r & 127;
    int L = m >> 1, half = m & 1;
    const float* W;
    if (L < 3) W = (half ? Wr : Wl) + (size_t)L * 16384;
    else W = c1W + (size_t)half * 16384;
    float v = W[k * 128 + n];
    __hip_bfloat16 hb = __float2bfloat16(v);
    float rl = v - __bfloat162float(hb);
    __hip_bfloat16 lb = __float2bfloat16(rl);
    wt[(size_t)m * 32768 + n * 128 + k] = *reinterpret_cast<unsigned short*>(&hb);
    wt[(size_t)m * 32768 + 16384 + n * 128 + k] = *reinterpret_cast<unsigned short*>(&lb);
}

// ---------------- dual GEMM via split-bf16 MFMA; bf16 outputs; optional fused encoder ----------------
// ENC: input hx is x [N][5]; h-tile computed inline as relu(x @ encW + encb)
template <bool ENC>
__global__ __launch_bounds__(256) void transform_mfma_kernel(const float* __restrict__ hx,
                                                             const unsigned short* __restrict__ wtA,
                                                             const float* __restrict__ bA,
                                                             const unsigned short* __restrict__ wtB,
                                                             const float* __restrict__ bB,
                                                             __hip_bfloat16* __restrict__ outA,
                                                             __hip_bfloat16* __restrict__ outB,
                                                             const float* __restrict__ encW,
                                                             const float* __restrict__ encb) {
    __shared__ __align__(16) char hhi[64 * 256];  // bf16 [64][128], XOR-swizzled 16B rows
    __shared__ __align__(16) char hlo[64 * 256];
    __shared__ float encWs[ENC ? 640 : 1];
    __shared__ float encbs[ENC ? 128 : 1];
    int t = threadIdx.x;
    int l = t & 63, w = t >> 6;
    int n0 = blockIdx.x * 64;

    if constexpr (ENC) {
        for (int i = t; i < 640; i += 256) encWs[i] = encW[i];
        if (t < 128) encbs[t] = encb[t];
        __syncthreads();
    }

    for (int i = t; i < 64 * 32; i += 256) {
        int row = i >> 5, c4 = (i & 31) * 4;
        int n = n0 + row;
        float4 v = make_float4(0.f, 0.f, 0.f, 0.f);
        if (n < N_NODES) {
            if constexpr (ENC) {
                float xv[5];
#pragma unroll
                for (int f = 0; f < 5; f++) xv[f] = hx[(size_t)n * 5 + f];
                float* pv = &v.x;
#pragma unroll
                for (int q = 0; q < 4; q++) {
                    int d = c4 + q;
                    float a = encbs[d];
#pragma unroll
                    for (int f = 0; f < 5; f++) a += xv[f] * encWs[f * 128 + d];
                    pv[q] = fmaxf(a, 0.f);
                }
            } else {
                v = *(const float4*)&hx[(size_t)n * DIM + c4];
            }
        }
        const float* pv = &v.x;
        unsigned short hi4[4], lo4[4];
#pragma unroll
        for (int q = 0; q < 4; q++) {
            __hip_bfloat16 hb = __float2bfloat16(pv[q]);
            float rl = pv[q] - __bfloat162float(hb);
            __hip_bfloat16 lb = __float2bfloat16(rl);
            hi4[q] = *reinterpret_cast<unsigned short*>(&hb);
            lo4[q] = *reinterpret_cast<unsigned short*>(&lb);
        }
        int addr = (row * 256 + c4 * 2) ^ ((row & 7) << 4);
        *(ushort4*)(hhi + addr) = make_ushort4(hi4[0], hi4[1], hi4[2], hi4[3]);
        *(ushort4*)(hlo + addr) = make_ushort4(lo4[0], lo4[1], lo4[2], lo4[3]);
    }
    __syncthreads();

    int lane_m = l & 15, lane_k8 = l >> 4;

#pragma unroll
    for (int mat = 0; mat < 2; mat++) {
        const short* wthi = (const short*)(mat ? wtB : wtA);
        const short* wtlo = wthi + 16384;
        const float* bias = mat ? bB : bA;
        short8 bh[2][4], bl_[2][4];
#pragma unroll
        for (int j = 0; j < 2; j++) {
            int nrow = (w * 2 + j) * 16 + lane_m;
#pragma unroll
            for (int ks = 0; ks < 4; ks++) {
                int ke = ks * 32 + lane_k8 * 8;
                bh[j][ks] = *(const short8*)(wthi + nrow * 128 + ke);
                bl_[j][ks] = *(const short8*)(wtlo + nrow * 128 + ke);
            }
        }
        f32x4 acc[4][2];
#pragma unroll
        for (int mt = 0; mt < 4; mt++)
#pragma unroll
            for (int j = 0; j < 2; j++) acc[mt][j] = (f32x4){0.f, 0.f, 0.f, 0.f};
#pragma unroll
        for (int ks = 0; ks < 4; ks++) {
            int kb = ks * 64 + lane_k8 * 16;
#pragma unroll
            for (int mt = 0; mt < 4; mt++) {
                int arow = mt * 16 + lane_m;
                int aswz = (arow & 7) << 4;
                short8 ahi = *(const short8*)(hhi + ((arow * 256 + kb) ^ aswz));
                short8 alo = *(const short8*)(hlo + ((arow * 256 + kb) ^ aswz));
#pragma unroll
                for (int j = 0; j < 2; j++) {
                    acc[mt][j] = __builtin_amdgcn_mfma_f32_16x16x32_bf16(ahi, bh[j][ks], acc[mt][j], 0, 0, 0);
                    acc[mt][j] = __builtin_amdgcn_mfma_f32_16x16x32_bf16(ahi, bl_[j][ks], acc[mt][j], 0, 0, 0);
                    acc[mt][j] = __builtin_amdgcn_mfma_f32_16x16x32_bf16(alo, bh[j][ks], acc[mt][j], 0, 0, 0);
                }
            }
        }
        __hip_bfloat16* outp = mat ? outB : outA;
#pragma unroll
        for (int j = 0; j < 2; j++) {
            int col = (w * 2 + j) * 16 + lane_m;
            float bv = bias ? bias[col] : 0.f;
#pragma unroll
            for (int mt = 0; mt < 4; mt++) {
#pragma unroll
                for (int r = 0; r < 4; r++) {
                    int node = n0 + mt * 16 + lane_k8 * 4 + r;
                    if (node < N_NODES) {
                        outp[(size_t)node * DIM + col] = __float2bfloat16(acc[mt][j][r] + bv);
                    }
                }
            }
        }
    }
}

// ---------------- GATv2 edge+aggregate v6: wave-per-node, bf16 xl+xr gathers, 8 edges/iter ----------------
__device__ __forceinline__ float4 bf4_to_f4(ushort4 u) {
    float4 v;
    v.x = __uint_as_float((unsigned)u.x << 16);
    v.y = __uint_as_float((unsigned)u.y << 16);
    v.z = __uint_as_float((unsigned)u.z << 16);
    v.w = __uint_as_float((unsigned)u.w << 16);
    return v;
}

__global__ __launch_bounds__(256) void gat_edge_kernel(const unsigned short* __restrict__ xl,
                                                       const unsigned short* __restrict__ xr,
                                                       const float* __restrict__ att, const float* __restrict__ gbias,
                                                       const int* __restrict__ indptr, const int* __restrict__ csr_src,
                                                       float* __restrict__ h_out) {
    int n = blockIdx.x * 4 + (threadIdx.x >> 6);  // wave-per-node
    int l = threadIdx.x & 63;
    int half = l >> 5;
    int c0 = (l & 31) * 4;
    float4 xrv = bf4_to_f4(*(const ushort4*)&xr[(size_t)n * DIM + c0]);
    float4 attv = *(const float4*)&att[c0];
    int beg = indptr[n], end = indptr[n + 1];

    float m[4], den[4];
    float4 acc[4];
    // self-loop seeds chain 0 of half 0
    {
        float4 v = bf4_to_f4(*(const ushort4*)&xl[(size_t)n * DIM + c0]);
        float z, a;
        z = v.x + xrv.x; z = fmaxf(z, NEG * z); a = z * attv.x;
        z = v.y + xrv.y; z = fmaxf(z, NEG * z); a += z * attv.y;
        z = v.z + xrv.z; z = fmaxf(z, NEG * z); a += z * attv.z;
        z = v.w + xrv.w; z = fmaxf(z, NEG * z); a += z * attv.w;
        a += __shfl_xor(a, 1);
        a += __shfl_xor(a, 2);
        a += __shfl_xor(a, 4);
        if (half == 0) {
            m[0] = a; den[0] = 1.f; acc[0] = v;
        } else {
            m[0] = -3.4e38f; den[0] = 0.f; acc[0] = make_float4(0.f, 0.f, 0.f, 0.f);
        }
#pragma unroll
        for (int c = 1; c < 4; c++) { m[c] = -3.4e38f; den[c] = 0.f; acc[c] = make_float4(0.f, 0.f, 0.f, 0.f); }
    }

    for (int i = beg; i < end; i += 8) {
        int s[4];
        bool val[4];
        float4 v[4];
        float a[4];
#pragma unroll
        for (int c = 0; c < 4; c++) {
            int idx = i + 2 * c + half;
            val[c] = idx < end;
            s[c] = val[c] ? csr_src[idx] : n;
        }
#pragma unroll
        for (int c = 0; c < 4; c++) v[c] = bf4_to_f4(*(const ushort4*)&xl[(size_t)s[c] * DIM + c0]);
#pragma unroll
        for (int c = 0; c < 4; c++) {
            float z, aa;
            z = v[c].x + xrv.x; z = fmaxf(z, NEG * z); aa = z * attv.x;
            z = v[c].y + xrv.y; z = fmaxf(z, NEG * z); aa += z * attv.y;
            z = v[c].z + xrv.z; z = fmaxf(z, NEG * z); aa += z * attv.z;
            z = v[c].w + xrv.w; z = fmaxf(z, NEG * z); aa += z * attv.w;
            a[c] = aa;
        }
#pragma unroll
        for (int off = 1; off <= 4; off <<= 1)
#pragma unroll
            for (int c = 0; c < 4; c++) a[c] += __shfl_xor(a[c], off);
#pragma unroll
        for (int c = 0; c < 4; c++) {
            if (!val[c]) a[c] = -3.4e38f;
            float mn = fmaxf(m[c], a[c]);
            float sc = __expf(m[c] - mn), p = __expf(a[c] - mn);
            den[c] = den[c] * sc + p;
            acc[c].x = acc[c].x * sc + p * v[c].x;
            acc[c].y = acc[c].y * sc + p * v[c].y;
            acc[c].z = acc[c].z * sc + p * v[c].z;
            acc[c].w = acc[c].w * sc + p * v[c].w;
            m[c] = mn;
        }
    }
    // merge 4 chains into chain 0 (lane-local)
#pragma unroll
    for (int c = 1; c < 4; c++) {
        float mm = fmaxf(m[0], m[c]);
        float s0 = __expf(m[0] - mm), s1 = __expf(m[c] - mm);
        den[0] = den[0] * s0 + den[c] * s1;
        acc[0].x = acc[0].x * s0 + acc[c].x * s1;
        acc[0].y = acc[0].y * s0 + acc[c].y * s1;
        acc[0].z = acc[0].z * s0 + acc[c].z * s1;
        acc[0].w = acc[0].w * s0 + acc[c].w * s1;
        m[0] = mm;
    }
    // merge across halves (lane l <-> l^32)
    {
        float mo = __shfl_xor(m[0], 32);
        float dno = __shfl_xor(den[0], 32);
        float4 ao;
        ao.x = __shfl_xor(acc[0].x, 32);
        ao.y = __shfl_xor(acc[0].y, 32);
        ao.z = __shfl_xor(acc[0].z, 32);
        ao.w = __shfl_xor(acc[0].w, 32);
        float mm = fmaxf(m[0], mo);
        float s0 = __expf(m[0] - mm), s1 = __expf(mo - mm);
        den[0] = den[0] * s0 + dno * s1;
        acc[0].x = acc[0].x * s0 + ao.x * s1;
        acc[0].y = acc[0].y * s0 + ao.y * s1;
        acc[0].z = acc[0].z * s0 + ao.z * s1;
        acc[0].w = acc[0].w * s0 + ao.w * s1;
    }
    if (half == 0) {
        float4 gb = *(const float4*)&gbias[c0];
        float inv = 1.f / (den[0] + 1e-16f);
        float4 o;
        o.x = acc[0].x * inv + gb.x;
        o.y = acc[0].y * inv + gb.y;
        o.z = acc[0].z * inv + gb.z;
        o.w = acc[0].w * inv + gb.w;
        o.x = (o.x > 0.f) ? o.x : __expf(o.x) - 1.f;
        o.y = (o.y > 0.f) ? o.y : __expf(o.y) - 1.f;
        o.z = (o.z > 0.f) ? o.z : __expf(o.z) - 1.f;
        o.w = (o.w > 0.f) ? o.w : __expf(o.w) - 1.f;
        *(float4*)&h_out[(size_t)n * DIM + c0] = o;
    }
}

// ---------------- edge MLP v7: CSR-ordered, 64-edge tiles, W2 hi/lo in REGISTERS, MFMA layer2 ----------------
__global__ __launch_bounds__(256) void edge_mlp_kernel(const unsigned* __restrict__ g1u, const unsigned* __restrict__ g2u,
                                                       const float* __restrict__ x,
                                                       const int* __restrict__ csr_src, const int* __restrict__ csr_dst,
                                                       const int* __restrict__ csr_eid,
                                                       const float* __restrict__ W1tail,  // c1_W rows 256,257
                                                       const float* __restrict__ W2, const float* __restrict__ b2,
                                                       const float* __restrict__ W3, const float* __restrict__ b3,
                                                       float* __restrict__ out, int ntiles) {
    __shared__ __align__(16) char smO1[64 * 256];  // 64 edges x 128 bf16, XOR-swizzled 16B
    __shared__ float smCw[2][128];
    __shared__ float smPart[4][64];
    __shared__ int rowi[64], coli[64], seid[64];
    __shared__ float sdt[64], sdi[64];
    int t = threadIdx.x;
    int l = t & 63, w = t >> 6;

    if (t < 128) {
        smCw[0][t] = W1tail[t];
        smCw[1][t] = W1tail[128 + t];
    }
    float b3v = b3[0];
    float b2v = b2[w * 16 + (l & 15)];
    float w3v = W3[w * 16 + (l & 15)];
    int koff = (l >> 4) * 16;

    // loop-invariant W2^T B-fragments -> registers (hi + lo split, loaded once)
    short8 bhi[4], blo[4];
    {
        int nrow = w * 16 + (l & 15);
        int kbase = (l >> 4) * 8;
#pragma unroll
        for (int ks = 0; ks < 4; ks++) {
            int ke = ks * 32 + kbase;
            short8 h8, l8;
#pragma unroll
            for (int q = 0; q < 8; q++) {
                float v = W2[(size_t)(ke + q) * 64 + nrow];
                __hip_bfloat16 hb = __float2bfloat16(v);
                float rl = v - __bfloat162float(hb);
                __hip_bfloat16 lb = __float2bfloat16(rl);
                h8[q] = *reinterpret_cast<short*>(&hb);
                l8[q] = *reinterpret_cast<short*>(&lb);
            }
            bhi[ks] = h8;
            blo[ks] = l8;
        }
    }

    const uint4* g1t = (const uint4*)g1u;
    const uint4* g2t = (const uint4*)g2u;

    for (int tile = blockIdx.x; tile < ntiles; tile += gridDim.x) {
        int p0 = tile * 64;
        __syncthreads();  // prev tile fully consumed (also first-iter smCw fence)
        if (t < 64) {
            int p = p0 + t;
            int r = csr_src[p], c = csr_dst[p];
            rowi[t] = r; coli[t] = c; seid[t] = csr_eid[p];
            sdt[t] = fabsf(x[r * 5 + 4] - x[c * 5 + 4]);
            float dx = x[r * 5 + 1] - x[c * 5 + 1];
            float dy = x[r * 5 + 2] - x[c * 5 + 2];
            float dz = x[r * 5 + 3] - x[c * 5 + 3];
            sdi[t] = sqrtf(dx * dx + dy * dy + dz * dz);
        }
        __syncthreads();
        // build o1: each thread one 16B slot (8 dims) of one edge; gathers interleaved
        for (int idx = t; idx < 64 * 16; idx += 256) {
            int e = idx >> 4, s4 = idx & 15;
            uint4 u1 = g1t[(size_t)rowi[e] * 16 + s4];
            uint4 u2 = g2t[(size_t)coli[e] * 16 + s4];
            float dtv = sdt[e], div = sdi[e];
            unsigned uo[4];
            const unsigned* a1 = &u1.x;
            const unsigned* a2 = &u2.x;
#pragma unroll
            for (int q = 0; q < 4; q++) {
                int d = s4 * 8 + q * 2;
                float lo = __uint_as_float(a1[q] << 16) + __uint_as_float(a2[q] << 16) + dtv * smCw[0][d] + div * smCw[1][d];
                float hi = __uint_as_float(a1[q] & 0xffff0000u) + __uint_as_float(a2[q] & 0xffff0000u) +
                           dtv * smCw[0][d + 1] + div * smCw[1][d + 1];
                lo = fmaxf(lo, 0.f); hi = fmaxf(hi, 0.f);
                __hip_bfloat16 blo16 = __float2bfloat16(lo), bhi16 = __float2bfloat16(hi);
                unsigned short ulo = *reinterpret_cast<unsigned short*>(&blo16);
                unsigned short uhi = *reinterpret_cast<unsigned short*>(&bhi16);
                uo[q] = (unsigned)ulo | ((unsigned)uhi << 16);
            }
            int addr = (e * 256 + s4 * 16) ^ ((e & 7) << 4);
            *(uint4*)(smO1 + addr) = *(uint4*)uo;
        }
        __syncthreads();
        // layer 2 via MFMA (W2 hi/lo from registers)
        f32x4 acc[4];
#pragma unroll
        for (int mt = 0; mt < 4; mt++) acc[mt] = (f32x4){0.f, 0.f, 0.f, 0.f};
#pragma unroll
        for (int ks = 0; ks < 4; ks++) {
#pragma unroll
            for (int mt = 0; mt < 4; mt++) {
                int mrow = mt * 16 + (l & 15);
                short8 afrag = *(const short8*)(smO1 + ((mrow * 256 + koff + ks * 64) ^ ((mrow & 7) << 4)));
                acc[mt] = __builtin_amdgcn_mfma_f32_16x16x32_bf16(afrag, bhi[ks], acc[mt], 0, 0, 0);
                acc[mt] = __builtin_amdgcn_mfma_f32_16x16x32_bf16(afrag, blo[ks], acc[mt], 0, 0, 0);
            }
        }
        // layer 3
        float p[4][4];
#pragma unroll
        for (int mt = 0; mt < 4; mt++)
#pragma unroll
            for (int r = 0; r < 4; r++) p[mt][r] = fmaxf(acc[mt][r] + b2v, 0.f) * w3v;
#pragma unroll
        for (int off = 8; off >= 1; off >>= 1)
#pragma unroll
            for (int mt = 0; mt < 4; mt++)
#pragma unroll
                for (int r = 0; r < 4; r++) p[mt][r] += __shfl_xor(p[mt][r], off);
        if ((l & 15) == 0) {
            int g = l >> 4;
#pragma unroll
            for (int mt = 0; mt < 4; mt++)
#pragma unroll
                for (int r = 0; r < 4; r++) smPart[w][mt * 16 + g * 4 + r] = p[mt][r];
        }
        __syncthreads();
        if (t < 64) out[seid[t]] = smPart[0][t] + smPart[1][t] + smPart[2][t] + smPart[3][t] + b3v;
    }
}

extern "C" void kernel_launch(void* const* d_in, const int* in_sizes, int n_in,
                              void* d_out, int out_size, void* d_ws, size_t ws_size,
                              hipStream_t stream) {
    const float* x = (const float*)d_in[0];
    const int* ei = (const int*)d_in[1];
    const float* enc_W = (const float*)d_in[2];
    const float* enc_b = (const float*)d_in[3];
    const float* Wl = (const float*)d_in[4];
    const float* bl = (const float*)d_in[5];
    const float* Wr = (const float*)d_in[6];
    const float* br = (const float*)d_in[7];
    const float* att = (const float*)d_in[8];
    const float* gbias = (const float*)d_in[9];
    const float* c1_W = (const float*)d_in[10];
    const float* c1_b = (const float*)d_in[11];
    const float* c2_W = (const float*)d_in[12];
    const float* c2_b = (const float*)d_in[13];
    const float* c3_W = (const float*)d_in[14];
    const float* c3_b = (const float*)d_in[15];
    float* out = (float*)d_out;

    float* h = (float*)d_ws;
    __hip_bfloat16* xl = (__hip_bfloat16*)(h + (size_t)N_NODES * DIM);  // bf16 xl / g1
    __hip_bfloat16* xr = xl + (size_t)N_NODES * DIM;                    // bf16 xr / g2
    int* csr_src = (int*)(xr + (size_t)N_NODES * DIM);
    int* csr_dst = csr_src + N_EDGES;
    int* csr_eid = csr_dst + N_EDGES;
    int* indptr = csr_eid + N_EDGES;
    int* counts = indptr + (N_NODES + 1);
    int* bsum = counts + N_NODES;
    int* boff = bsum + 256;
    uintptr_t wp = (uintptr_t)(boff + 256);
    wp = (wp + 15) & ~(uintptr_t)15;
    unsigned short* wt = (unsigned short*)wp;  // 8 matrices x {hi,lo} x 16384 bf16 = 512 KB

    const int* srcp = ei;
    const int* dstp = ei + N_EDGES;
    const int NB = (N_NODES + 255) / 256;   // 196
    const int TGRID = (N_NODES + 63) / 64;  // 782

    // weight prep (transpose + hi/lo split) + zero counts
    prep_weights_kernel<<<8 * 16384 / 256, 256, 0, stream>>>(Wl, Wr, c1_W, wt, counts);

    // CSR build
    hist_kernel<<<N_EDGES / 256, 256, 0, stream>>>(dstp, counts);
    scan1_kernel<<<NB, 256, 0, stream>>>(counts, indptr, bsum, N_NODES);
    scan2_kernel<<<1, 256, 0, stream>>>(bsum, boff, indptr, NB);
    scan3_kernel<<<NB, 256, 0, stream>>>(indptr, boff, N_NODES);
    place_kernel<<<N_EDGES / 256, 256, 0, stream>>>(srcp, dstp, indptr, counts, csr_src, csr_dst, csr_eid);

    // GAT layers (xl, xr both bf16); layer 0 fuses the encoder
    for (int i = 0; i < NLAYER; i++) {
        if (i == 0) {
            transform_mfma_kernel<true><<<TGRID, 256, 0, stream>>>(
                x, wt + (size_t)0 * 32768, bl,
                wt + (size_t)1 * 32768, br, xl, xr, enc_W, enc_b);
        } else {
            transform_mfma_kernel<false><<<TGRID, 256, 0, stream>>>(
                h, wt + (size_t)(i * 2) * 32768, bl + (size_t)i * DIM,
                wt + (size_t)(i * 2 + 1) * 32768, br + (size_t)i * DIM, xl, xr, nullptr, nullptr);
        }
        gat_edge_kernel<<<N_NODES / 4, 256, 0, stream>>>((const unsigned short*)xl, (const unsigned short*)xr,
                                                         att + (size_t)i * DIM,
                                                         gbias + (size_t)i * DIM, indptr, csr_src, h);
    }

    // classifier layer-1 node-level split: g1 = h@W1a + b1, g2 = h@W1b (both bf16)
    transform_mfma_kernel<false><<<TGRID, 256, 0, stream>>>(
        h, wt + (size_t)6 * 32768, c1_b, wt + (size_t)7 * 32768, nullptr, xl, xr, nullptr, nullptr);

    // fused edge MLP (CSR-ordered, 64-edge tiles, register-W2 MFMA layer2)
    edge_mlp_kernel<<<2048, 256, 0, stream>>>((const unsigned*)xl, (const unsigned*)xr, x,
                                              csr_src, csr_dst, csr_eid, c1_W + 256 * DIM,
                                              c2_W, c2_b, c3_W, c3_b, out, N_EDGES / 64);
}